// Round 1
// baseline (656.604 us; speedup 1.0000x reference)
//
#include <hip/hip_runtime.h>

#define TM 64
#define TN 64
#define TK 16

// C[b] = A[b] (MxK) @ Bm[b] (KxN), all row-major, batched over blockIdx.z
__global__ __launch_bounds__(256)
void gemm_bk(const float* __restrict__ A, const float* __restrict__ Bm,
             float* __restrict__ C, int M, int N, int Kd) {
  const int b = blockIdx.z;
  const int row0 = blockIdx.y * TM;
  const int col0 = blockIdx.x * TN;
  const float* Ab = A + (size_t)b * M * Kd;
  const float* Bb = Bm + (size_t)b * Kd * N;
  float* Cb = C + (size_t)b * M * N;

  __shared__ float As[TK][TM + 4];  // transposed A tile, padded
  __shared__ float Bs[TK][TN];

  const int tid = threadIdx.x;
  const int tx = tid & 15;   // n-dir
  const int ty = tid >> 4;   // m-dir

  float acc[4][4] = {};

  for (int k0 = 0; k0 < Kd; k0 += TK) {
    // A tile: 64 rows x 16 k. thread t loads float4 at (m = t>>2, kk = (t&3)*4)
    {
      const int m = tid >> 2;
      const int kk = (tid & 3) * 4;
      const float4 av = *(const float4*)(Ab + (size_t)(row0 + m) * Kd + k0 + kk);
      As[kk + 0][m] = av.x;
      As[kk + 1][m] = av.y;
      As[kk + 2][m] = av.z;
      As[kk + 3][m] = av.w;
    }
    // B tile: 16 k x 64 n. thread t loads float4 at (kk = t>>4, n = (t&15)*4)
    {
      const int kk = tid >> 4;
      const int n = (tid & 15) * 4;
      *(float4*)&Bs[kk][n] = *(const float4*)(Bb + (size_t)(k0 + kk) * N + col0 + n);
    }
    __syncthreads();
#pragma unroll
    for (int kk = 0; kk < TK; ++kk) {
      const float4 av = *(const float4*)&As[kk][ty * 4];
      const float4 bv = *(const float4*)&Bs[kk][tx * 4];
      acc[0][0] += av.x * bv.x; acc[0][1] += av.x * bv.y; acc[0][2] += av.x * bv.z; acc[0][3] += av.x * bv.w;
      acc[1][0] += av.y * bv.x; acc[1][1] += av.y * bv.y; acc[1][2] += av.y * bv.z; acc[1][3] += av.y * bv.w;
      acc[2][0] += av.z * bv.x; acc[2][1] += av.z * bv.y; acc[2][2] += av.z * bv.z; acc[2][3] += av.z * bv.w;
      acc[3][0] += av.w * bv.x; acc[3][1] += av.w * bv.y; acc[3][2] += av.w * bv.z; acc[3][3] += av.w * bv.w;
    }
    __syncthreads();
  }
#pragma unroll
  for (int j = 0; j < 4; ++j) {
    float4 r;
    r.x = acc[j][0]; r.y = acc[j][1]; r.z = acc[j][2]; r.w = acc[j][3];
    *(float4*)(Cb + (size_t)(row0 + ty * 4 + j) * N + col0 + tx * 4) = r;
  }
}

// Per (b, q): out[b, :, q, :] = M(64x96) @ V(96x64) + bias
// V rows: cc=3c+0 -> x0[b,q,c,:], 3c+1 -> x1, 3c+2 -> y2
// M[o][3c+0] = W[o][3c] - W[o][3c+2]; M[o][3c+1] = W[o][3c+1]; M[o][3c+2] = 2*W[o][3c+2]
__global__ __launch_bounds__(256)
void mix_k(const float* __restrict__ x0, const float* __restrict__ x1,
           const float* __restrict__ y2, const float* __restrict__ W,
           const float* __restrict__ bias, float* __restrict__ out) {
  const int q = blockIdx.x;  // 0..511
  const int b = blockIdx.y;  // 0..15
  __shared__ float Vs[96][64];
  __shared__ float Ms[96][68];  // [cc][o], padded

  const int tid = threadIdx.x;

  for (int i = tid; i < 64 * 96; i += 256) {
    const int o = i / 96;
    const int cc = i % 96;
    const int k = cc % 3;
    const float w = W[o * 96 + cc];
    float m;
    if (k == 0) m = w - W[o * 96 + cc + 2];
    else if (k == 1) m = w;
    else m = 2.0f * w;
    Ms[cc][o] = m;
  }

  const size_t base = ((size_t)b * 512 + q) * 2048;
  for (int i = tid * 4; i < 2048; i += 256 * 4) {
    const int c = i >> 6;
    const int l = i & 63;
    *(float4*)&Vs[3 * c + 0][l] = *(const float4*)(x0 + base + i);
    *(float4*)&Vs[3 * c + 1][l] = *(const float4*)(x1 + base + i);
    *(float4*)&Vs[3 * c + 2][l] = *(const float4*)(y2 + base + i);
  }
  __syncthreads();

  const int lx = tid & 15, oy = tid >> 4;
  const int l0 = lx * 4, o0 = oy * 4;
  float acc[4][4] = {};  // [o][l]
#pragma unroll
  for (int cc = 0; cc < 96; ++cc) {
    const float4 v = *(const float4*)&Vs[cc][l0];
    const float4 m = *(const float4*)&Ms[cc][o0];
    acc[0][0] += m.x * v.x; acc[0][1] += m.x * v.y; acc[0][2] += m.x * v.z; acc[0][3] += m.x * v.w;
    acc[1][0] += m.y * v.x; acc[1][1] += m.y * v.y; acc[1][2] += m.y * v.z; acc[1][3] += m.y * v.w;
    acc[2][0] += m.z * v.x; acc[2][1] += m.z * v.y; acc[2][2] += m.z * v.z; acc[2][3] += m.z * v.w;
    acc[3][0] += m.w * v.x; acc[3][1] += m.w * v.y; acc[3][2] += m.w * v.z; acc[3][3] += m.w * v.w;
  }
#pragma unroll
  for (int j = 0; j < 4; ++j) {
    const float bo = bias[o0 + j];
    float4 r;
    r.x = acc[j][0] + bo; r.y = acc[j][1] + bo; r.z = acc[j][2] + bo; r.w = acc[j][3] + bo;
    *(float4*)(out + (((size_t)b * 64 + o0 + j) * 512 + q) * 64 + l0) = r;
  }
}

extern "C" void kernel_launch(void* const* d_in, const int* in_sizes, int n_in,
                              void* d_out, int out_size, void* d_ws, size_t ws_size,
                              hipStream_t stream) {
  const float* x   = (const float*)d_in[0];  // [16,512,32,64]
  const float* adj = (const float*)d_in[1];  // [16,512,512]
  const float* W   = (const float*)d_in[2];  // [64,96]
  const float* bia = (const float*)d_in[3];  // [64]
  float* out = (float*)d_out;                // [16,64,512,64]

  const int Bn = 16, N = 512, CL = 2048;
  float* X1 = (float*)d_ws;                      // [16,512,2048]
  float* Y2 = X1 + (size_t)Bn * N * CL;          // [16,512,2048]

  dim3 gg(CL / TN, N / TM, Bn);  // (32, 8, 16)
  // X1 = adj @ X
  hipLaunchKernelGGL(gemm_bk, gg, dim3(256), 0, stream, adj, x, X1, N, CL, N);
  // Y2 = adj @ X1
  hipLaunchKernelGGL(gemm_bk, gg, dim3(256), 0, stream, adj, X1, Y2, N, CL, N);
  // mix
  hipLaunchKernelGGL(mix_k, dim3(N, Bn), dim3(256), 0, stream, x, X1, Y2, W, bia, out);
}

// Round 2
// 151.215 us; speedup vs baseline: 4.3422x; 4.3422x over previous
//
#include <hip/hip_runtime.h>

typedef unsigned short u16;
typedef __bf16 v8bf __attribute__((ext_vector_type(8)));
typedef float f32x4 __attribute__((ext_vector_type(4)));
typedef u16 us8 __attribute__((ext_vector_type(8)));

static __device__ __forceinline__ u16 f2bf(float f) {
  union { __bf16 h; u16 u; } cv;
  cv.h = (__bf16)f;
  return cv.u;
}

// ---- fp32 -> bf16 elementwise, 8 elems/thread ----
__global__ __launch_bounds__(256)
void cvt_f2bf_k(const float* __restrict__ in, u16* __restrict__ out, int n8) {
  const int i = blockIdx.x * 256 + threadIdx.x;
  if (i >= n8) return;
  const float4 a = ((const float4*)in)[2 * i];
  const float4 b = ((const float4*)in)[2 * i + 1];
  us8 r;
  r[0] = f2bf(a.x); r[1] = f2bf(a.y); r[2] = f2bf(a.z); r[3] = f2bf(a.w);
  r[4] = f2bf(b.x); r[5] = f2bf(b.y); r[6] = f2bf(b.z); r[7] = f2bf(b.w);
  ((us8*)out)[i] = r;
}

// ---- fold W into mix matrix M (bf16): M[o][3c]=W0-W2, M[o][3c+1]=W1, M[o][3c+2]=2*W2 ----
__global__ __launch_bounds__(256)
void foldw_k(const float* __restrict__ W, u16* __restrict__ Mb) {
  const int i = blockIdx.x * 256 + threadIdx.x;
  if (i >= 64 * 96) return;
  const int cc = i % 96;
  const int r = cc % 3;
  const float w = W[i];
  const float m = (r == 0) ? (w - W[i + 2]) : ((r == 1) ? w : 2.0f * w);
  Mb[i] = f2bf(m);
}

// ---- C[b] (512x2048 bf16) = A[b] (512x512 bf16) @ B[b] (512x2048 bf16), fp32 accum ----
#define BM 128
#define BN 128
#define BK 32

__global__ __launch_bounds__(256)
void gemm_bf16(const u16* __restrict__ A, const u16* __restrict__ Bm,
               u16* __restrict__ C) {
  const int b = blockIdx.z;
  const int row0 = blockIdx.y * BM;
  const int col0 = blockIdx.x * BN;
  const u16* Ab = A + (size_t)b * 512 * 512;
  const u16* Bb = Bm + (size_t)b * 512 * 2048;
  u16* Cb = C + (size_t)b * 512 * 2048;

  __shared__ u16 As[BM][BK + 8];  // [row][k], 80B rows -> friendly bank pattern
  __shared__ u16 Bs[BN][BK + 8];  // [col][k]

  const int tid = threadIdx.x;
  const int lane = tid & 63;
  const int w = tid >> 6;
  const int wm = (w >> 1) * 64;
  const int wn = (w & 1) * 64;
  const int l16 = lane & 15;
  const int kg = lane >> 4;

  f32x4 acc[4][4];
#pragma unroll
  for (int m = 0; m < 4; ++m)
#pragma unroll
    for (int n = 0; n < 4; ++n)
      acc[m][n] = (f32x4){0.f, 0.f, 0.f, 0.f};

  for (int k0 = 0; k0 < 512; k0 += BK) {
    // A tile: rows contiguous in k -> 16B load + 16B LDS write
#pragma unroll
    for (int i = 0; i < 2; ++i) {
      const int idx = tid + 256 * i;
      const int r = idx >> 2;
      const int ka = (idx & 3) * 8;
      *(uint4*)&As[r][ka] = *(const uint4*)(Ab + (size_t)(row0 + r) * 512 + k0 + ka);
    }
    // B tile transposed: thread owns (col n, 8 consecutive k); 8 scalar global
    // loads (each wave-coalesced: consecutive lanes -> consecutive cols) then
    // ONE b128 LDS write (no 16-way conflicts, no runtime-indexed reg arrays).
#pragma unroll
    for (int i = 0; i < 2; ++i) {
      const int idx = tid + 256 * i;
      const int n = idx & 127;
      const int kb = (idx >> 7) * 8;
      const u16* src = Bb + (size_t)(k0 + kb) * 2048 + col0 + n;
      us8 v;
#pragma unroll
      for (int j = 0; j < 8; ++j) v[j] = src[(size_t)j * 2048];
      *(us8*)&Bs[n][kb] = v;
    }
    __syncthreads();
    v8bf af[4], bfr[4];
#pragma unroll
    for (int m = 0; m < 4; ++m) af[m] = *(const v8bf*)&As[wm + m * 16 + l16][kg * 8];
#pragma unroll
    for (int n = 0; n < 4; ++n) bfr[n] = *(const v8bf*)&Bs[wn + n * 16 + l16][kg * 8];
#pragma unroll
    for (int m = 0; m < 4; ++m)
#pragma unroll
      for (int n = 0; n < 4; ++n)
        acc[m][n] = __builtin_amdgcn_mfma_f32_16x16x32_bf16(af[m], bfr[n], acc[m][n], 0, 0, 0);
    __syncthreads();
  }
  // C/D layout (m89-verified): col = lane&15, row = (lane>>4)*4 + reg
#pragma unroll
  for (int m = 0; m < 4; ++m)
#pragma unroll
    for (int n = 0; n < 4; ++n)
#pragma unroll
      for (int v = 0; v < 4; ++v) {
        const int rr = row0 + wm + m * 16 + kg * 4 + v;
        const int cc = col0 + wn + n * 16 + l16;
        Cb[(size_t)rr * 2048 + cc] = f2bf(acc[m][n][v]);
      }
}

// ---- mix: per (b,q): out[b,:,q,:] = M(64x96) @ V(96x64) + bias ----
// V rows: 3c -> x (fp32, cvt), 3c+1 -> X1 (bf16), 3c+2 -> Y2 (bf16)
__global__ __launch_bounds__(256)
void mix_mfma(const float* __restrict__ x0, const u16* __restrict__ x1,
              const u16* __restrict__ y2, const u16* __restrict__ Mb,
              const float* __restrict__ bias, float* __restrict__ out) {
  const int q = blockIdx.x;
  const int b = blockIdx.y;
  __shared__ u16 Vt[64][104];  // [l][cc] (transposed V), 208B rows
  __shared__ u16 Ms[64][104];  // [o][cc]
  const int tid = threadIdx.x;
  const int lane = tid & 63;
  const int w = tid >> 6;
  const int l16 = lane & 15;
  const int kg = lane >> 4;

#pragma unroll
  for (int i = 0; i < 3; ++i) {
    const int idx = tid + 256 * i;  // 0..767 covers 64x96/8
    const int o = idx / 12;
    const int c8 = (idx % 12) * 8;
    *(uint4*)&Ms[o][c8] = *(const uint4*)(Mb + o * 96 + c8);
  }
  const size_t base = ((size_t)b * 512 + q) * 2048;
#pragma unroll
  for (int i = 0; i < 2; ++i) {
    const int idx = tid + 256 * i;  // 512 float4 chunks
    const int c = idx >> 4;
    const int l0 = (idx & 15) * 4;
    const float4 v = *(const float4*)(x0 + base + c * 64 + l0);
    Vt[l0 + 0][3 * c] = f2bf(v.x);
    Vt[l0 + 1][3 * c] = f2bf(v.y);
    Vt[l0 + 2][3 * c] = f2bf(v.z);
    Vt[l0 + 3][3 * c] = f2bf(v.w);
  }
  {
    const int c = tid >> 3;
    const int l0 = (tid & 7) * 8;
    const us8 v1 = *(const us8*)(x1 + base + c * 64 + l0);
    const us8 v2 = *(const us8*)(y2 + base + c * 64 + l0);
#pragma unroll
    for (int j = 0; j < 8; ++j) {
      Vt[l0 + j][3 * c + 1] = v1[j];
      Vt[l0 + j][3 * c + 2] = v2[j];
    }
  }
  __syncthreads();

  f32x4 acc[4];
#pragma unroll
  for (int n = 0; n < 4; ++n) acc[n] = (f32x4){0.f, 0.f, 0.f, 0.f};
#pragma unroll
  for (int ks = 0; ks < 3; ++ks) {
    const v8bf a = *(const v8bf*)&Ms[w * 16 + l16][ks * 32 + kg * 8];
#pragma unroll
    for (int n = 0; n < 4; ++n) {
      const v8bf bv = *(const v8bf*)&Vt[n * 16 + l16][ks * 32 + kg * 8];
      acc[n] = __builtin_amdgcn_mfma_f32_16x16x32_bf16(a, bv, acc[n], 0, 0, 0);
    }
  }
#pragma unroll
  for (int n = 0; n < 4; ++n)
#pragma unroll
    for (int v = 0; v < 4; ++v) {
      const int o = w * 16 + kg * 4 + v;
      out[(((size_t)b * 64 + o) * 512 + q) * 64 + n * 16 + l16] = acc[n][v] + bias[o];
    }
}

extern "C" void kernel_launch(void* const* d_in, const int* in_sizes, int n_in,
                              void* d_out, int out_size, void* d_ws, size_t ws_size,
                              hipStream_t stream) {
  const float* x   = (const float*)d_in[0];  // [16,512,32,64]
  const float* adj = (const float*)d_in[1];  // [16,512,512]
  const float* W   = (const float*)d_in[2];  // [64,96]
  const float* bia = (const float*)d_in[3];  // [64]
  float* out = (float*)d_out;                // [16,64,512,64]

  u16* adj_bf = (u16*)d_ws;                                 // 4,194,304
  u16* x_bf   = adj_bf + (size_t)16 * 512 * 512;            // 16,777,216
  u16* X1     = x_bf   + (size_t)16 * 512 * 2048;
  u16* Y2     = X1     + (size_t)16 * 512 * 2048;
  u16* Mb     = Y2     + (size_t)16 * 512 * 2048;           // 6144

  const int n8_adj = 16 * 512 * 512 / 8;    // 524288
  const int n8_x   = 16 * 512 * 2048 / 8;   // 2097152
  hipLaunchKernelGGL(cvt_f2bf_k, dim3(n8_adj / 256), dim3(256), 0, stream, adj, adj_bf, n8_adj);
  hipLaunchKernelGGL(cvt_f2bf_k, dim3(n8_x / 256), dim3(256), 0, stream, x, x_bf, n8_x);
  hipLaunchKernelGGL(foldw_k, dim3(24), dim3(256), 0, stream, W, Mb);

  dim3 gg(2048 / BN, 512 / BM, 16);  // (16, 4, 16)
  hipLaunchKernelGGL(gemm_bf16, gg, dim3(256), 0, stream, adj_bf, x_bf, X1);
  hipLaunchKernelGGL(gemm_bf16, gg, dim3(256), 0, stream, adj_bf, X1, Y2);

  hipLaunchKernelGGL(mix_mfma, dim3(512, 16), dim3(256), 0, stream, x, X1, Y2, Mb, bia, out);
}